// Round 10
// baseline (1690.970 us; speedup 1.0000x reference)
//
#include <hip/hip_runtime.h>
#include <stdint.h>

#define T_TOK 32768
#define H_DIM 1024
#define NH    12
#define HK    64
#define HV    128
#define KD    768
#define VD    1536
#define NSEG  16
#define NCOL  2432
#define FEAT  48
#define CHUNK_M 4096
#define NSLOT (T_TOK/8 + 32)
#define MAXSB 96
#define OCH   8

typedef unsigned int uint;
typedef unsigned short ushort;

typedef short bf16x8_t __attribute__((ext_vector_type(8)));
typedef float f32x4_t  __attribute__((ext_vector_type(4)));

__device__ __forceinline__ ushort f2b(float f){
  uint u = __float_as_uint(f);
  u += 0x7fffu + ((u>>16)&1u);
  return (ushort)(u>>16);
}
__device__ __forceinline__ float b2f(ushort u){ return __uint_as_float(((uint)u)<<16); }
__device__ __forceinline__ void unpack2(uint u, float&a, float&b){
  a = __uint_as_float(u<<16); b = __uint_as_float(u & 0xffff0000u);
}
__device__ __forceinline__ float sigm(float x){ return 1.f/(1.f + __expf(-x)); }
__device__ __forceinline__ float silu(float x){ return x * sigm(x); }

// async global->LDS, 16B per lane; LDS dest = wave-uniform base + lane*16
__device__ __forceinline__ void gl16(const ushort* g, ushort* l){
  __builtin_amdgcn_global_load_lds(
    (const __attribute__((address_space(1))) uint*)g,
    (__attribute__((address_space(3))) uint*)l, 16, 0, 0);
}

// ---------------- seg_id ----------------
__global__ void segk(const int* __restrict__ cu, int* __restrict__ seg){
  int t = blockIdx.x*256 + threadIdx.x;
  if (t >= T_TOK) return;
  int s = 0;
  #pragma unroll
  for (int i=1;i<=NSEG;i++) s += (cu[i] <= t) ? 1 : 0;
  seg[t] = s;
}

// ---------------- stage A ----------------
__global__ __launch_bounds__(256,1) void stage_a(const float* __restrict__ x,
   const int* __restrict__ atype, const float* __restrict__ ac_table,
   const float* __restrict__ W_in, const float* __restrict__ b_in,
   const float* __restrict__ norm_w, const int* __restrict__ seg, int row_base,
   ushort* __restrict__ hn, float* __restrict__ h_end, float* __restrict__ hn_ends)
{
  __shared__ float feat[8][FEAT];
  __shared__ float hbuf[8][H_DIM];
  __shared__ float red[8];
  int tid = threadIdx.x;
  int base = row_base + blockIdx.x*8;
  int lbase = blockIdx.x*8;
  if (tid < 8) red[tid] = 0.f;
  for (int idx=tid; idx<8*FEAT; idx+=256){
    int rr = idx / FEAT, i = idx % FEAT;
    int t = base + rr;
    float v;
    if (i < 16) v = x[t*16 + i];
    else { int s = seg[t]; int a = atype[s]; v = ac_table[a*32 + (i-16)]; }
    feat[rr][i] = v;
  }
  __syncthreads();
  int c0 = tid*4;
  int lane = tid & 63;
  float4 bi = *(const float4*)&b_in[c0];
  for (int rc=0; rc<2; rc++){
    float acc[4][4];
    #pragma unroll
    for (int r4=0;r4<4;r4++){ acc[r4][0]=bi.x; acc[r4][1]=bi.y; acc[r4][2]=bi.z; acc[r4][3]=bi.w; }
    for (int i=0;i<FEAT;i++){
      float4 wu = *(const float4*)&W_in[i*H_DIM + c0];
      #pragma unroll
      for (int r4=0;r4<4;r4++){
        float f = feat[rc*4+r4][i];
        acc[r4][0] = fmaf(f,wu.x,acc[r4][0]);
        acc[r4][1] = fmaf(f,wu.y,acc[r4][1]);
        acc[r4][2] = fmaf(f,wu.z,acc[r4][2]);
        acc[r4][3] = fmaf(f,wu.w,acc[r4][3]);
      }
    }
    #pragma unroll
    for (int r4=0;r4<4;r4++){
      int rr = rc*4+r4;
      float sq = acc[r4][0]*acc[r4][0] + acc[r4][1]*acc[r4][1]
               + acc[r4][2]*acc[r4][2] + acc[r4][3]*acc[r4][3];
      #pragma unroll
      for (int off=1; off<64; off<<=1) sq += __shfl_xor(sq, off);
      if (lane==0) atomicAdd(&red[rr], sq);
      hbuf[rr][c0]=acc[r4][0]; hbuf[rr][c0+1]=acc[r4][1];
      hbuf[rr][c0+2]=acc[r4][2]; hbuf[rr][c0+3]=acc[r4][3];
    }
  }
  __syncthreads();
  float4 nw = *(const float4*)&norm_w[c0];
  for (int rr=0; rr<8; rr++){
    int t = base + rr;
    float sc = rsqrtf(red[rr]*(1.f/1024.f) + 1e-6f);
    float h0=hbuf[rr][c0], h1=hbuf[rr][c0+1], h2=hbuf[rr][c0+2], h3=hbuf[rr][c0+3];
    float n0=h0*sc*(1.f+nw.x), n1=h1*sc*(1.f+nw.y);
    float n2=h2*sc*(1.f+nw.z), n3=h3*sc*(1.f+nw.w);
    uint2 ov; ov.x = (uint)f2b(n0) | ((uint)f2b(n1)<<16);
    ov.y = (uint)f2b(n2) | ((uint)f2b(n3)<<16);
    *(uint2*)&hn[(size_t)(lbase+rr)*H_DIM + c0] = ov;
    int sgt = seg[t];
    bool isend = (t == T_TOK-1) || (seg[t+1] != sgt);
    if (isend){
      float* he = h_end + (size_t)sgt*H_DIM + c0;
      he[0]=h0; he[1]=h1; he[2]=h2; he[3]=h3;
    }
    #pragma unroll
    for (int d=0; d<4; d++){
      int td = t + d;
      if (td < T_TOK && seg[td] == sgt){
        bool end2 = (td == T_TOK-1) || (seg[td+1] != sgt);
        if (end2){
          float* hd = hn_ends + ((size_t)sgt*4 + (3-d))*H_DIM + c0;
          hd[0]=n0; hd[1]=n1; hd[2]=n2; hd[3]=n3;
        }
      }
    }
  }
}

// ---------------- build fused transposed weight ----------------
__global__ void build_wt(const float* __restrict__ Wk, const float* __restrict__ Wv,
                         const float* __restrict__ Wb, const float* __restrict__ Wa,
                         ushort* __restrict__ wt)
{
  int idx = blockIdx.x*256 + threadIdx.x;
  int n = idx >> 10, k = idx & 1023;
  float v;
  if      (n < 768)  v = Wk[k*768 + n];
  else if (n < 2304) v = Wv[k*1536 + (n-768)];
  else if (n < 2316) v = Wb[k*12 + (n-2304)];
  else if (n < 2328) v = Wa[k*12 + (n-2316)];
  else               v = 0.f;
  wt[idx] = f2b(v);
}

// ---------------- chunked MFMA GEMM, m97-style global_load_lds staging ----------
__global__ __launch_bounds__(256,1) void gemm_bf16(const ushort* __restrict__ A,
    const ushort* __restrict__ Bt, int row_base,
    ushort* __restrict__ kpre, ushort* __restrict__ vpre, float* __restrict__ ba)
{
  const int K = H_DIM;
  __shared__ ushort As[128*32];
  __shared__ ushort Bs[128*32];
  int tid = threadIdx.x;
  const int ntile = NCOL >> 7;
  int mt = blockIdx.x / ntile, nt = blockIdx.x % ntile;
  int m0 = mt<<7, n0 = nt<<7;
  int lane = tid & 63;
  int wv = tid >> 6;
  // staging map: lane l of wave w covers row w*16 + (l>>2), cols (l&3)*8..+8
  int rS = wv*16 + (lane>>2);
  int cS = (lane&3)<<3;
  const ushort* pa0 = A  + (size_t)(m0 + rS)*K + cS;
  const ushort* pa1 = A  + (size_t)(m0 + rS + 64)*K + cS;
  const ushort* pb0 = Bt + (size_t)(n0 + rS)*K + cS;
  const ushort* pb1 = Bt + (size_t)(n0 + rS + 64)*K + cS;
  ushort* lA0 = &As[wv*512];
  ushort* lA1 = &As[2048 + wv*512];
  ushort* lB0 = &Bs[wv*512];
  ushort* lB1 = &Bs[2048 + wv*512];
  int wm = (wv>>1)<<6, wn = (wv&1)<<6;
  int mloc = lane & 15, q8 = (lane>>4)<<3;
  f32x4_t acc[4][4];
  f32x4_t zero = {0.f,0.f,0.f,0.f};
  #pragma unroll
  for (int i=0;i<4;i++)
    #pragma unroll
    for (int j=0;j<4;j++) acc[i][j] = zero;
  for (int kk=0; kk<K; kk+=32){
    __syncthreads();                 // prior-iter LDS reads done before overwrite
    gl16(pa0 + kk, lA0);
    gl16(pa1 + kk, lA1);
    gl16(pb0 + kk, lB0);
    gl16(pb1 + kk, lB1);
    __syncthreads();                 // staging (vmcnt) drained
    bf16x8_t af[4], bfr[4];
    #pragma unroll
    for (int i=0;i<4;i++){
      af[i]  = *(const bf16x8_t*)&As[(wm + i*16 + mloc)*32 + q8];
      bfr[i] = *(const bf16x8_t*)&Bs[(wn + i*16 + mloc)*32 + q8];
    }
    #pragma unroll
    for (int i=0;i<4;i++)
      #pragma unroll
      for (int j=0;j<4;j++)
        acc[i][j] = __builtin_amdgcn_mfma_f32_16x16x32_bf16(af[i], bfr[j], acc[i][j], 0,0,0);
  }
  int rq = (lane>>4)<<2;
  if (nt < 18){
    ushort* dst; int nstr, cbase;
    if (nt < 6) { dst = kpre; nstr = KD; cbase = n0; }
    else        { dst = vpre; nstr = VD; cbase = n0 - KD; }
    #pragma unroll
    for (int i=0;i<4;i++){
      #pragma unroll
      for (int j=0;j<4;j++){
        int colg = cbase + wn + j*16 + mloc;
        #pragma unroll
        for (int rg=0; rg<4; rg++){
          int rowg = row_base + m0 + wm + i*16 + rq + rg;
          dst[(size_t)rowg*nstr + colg] = f2b(acc[i][j][rg]);
        }
      }
    }
  } else {
    #pragma unroll
    for (int i=0;i<4;i++){
      #pragma unroll
      for (int j=0;j<4;j++){
        int cl = wn + j*16 + mloc;
        if (cl >= 24) continue;
        #pragma unroll
        for (int rg=0; rg<4; rg++){
          int rowg = row_base + m0 + wm + i*16 + rq + rg;
          ba[(size_t)rowg*32 + cl] = acc[i][j][rg];
        }
      }
    }
  }
}

// ---------------- decay/beta ----------------
__global__ void dbk(const float* __restrict__ ba, const float* __restrict__ A_log,
                    const float* __restrict__ dt_bias, float2* __restrict__ db)
{
  int idx = blockIdx.x*256 + threadIdx.x;
  if (idx >= T_TOK*NH) return;
  int t = idx / NH, hh = idx % NH;
  float bp = ba[(size_t)t*32 + hh];
  float ap = ba[(size_t)t*32 + 12 + hh] + dt_bias[hh];
  float beta = sigm(bp);
  float sp = (ap > 20.f) ? ap : log1pf(__expf(ap));
  float dec = __expf(-__expf(A_log[hh]) * sp);
  float2 o; o.x = dec; o.y = beta;
  db[idx] = o;
}

// ---------------- side rows for conv ----------------
__global__ void side_k(const ushort* __restrict__ kpre, const ushort* __restrict__ vpre,
                       ushort* __restrict__ side)
{
  int b = blockIdx.x;
  int base = b*64;
  for (int idx=threadIdx.x; idx<3*2304; idx+=256){
    int jrow = idx / 2304, c = idx % 2304;
    int t0 = base - 3 + jrow;
    ushort v = 0;
    if (t0 >= 0)
      v = (c < KD) ? kpre[(size_t)t0*KD + c] : vpre[(size_t)t0*VD + (c-KD)];
    side[(size_t)(b*3 + jrow)*2304 + c] = v;
  }
}

// ---------------- conv+silu (+l2norm k) in place ----------------
__global__ __launch_bounds__(256,1) void conv_ip(ushort* __restrict__ kpre,
   ushort* __restrict__ vpre, const ushort* __restrict__ side,
   const int* __restrict__ seg, const float* __restrict__ ckw, const float* __restrict__ cvw)
{
  int tid = threadIdx.x;
  int b = blockIdx.x;
  int base = b * 64;
  float w[9][4];
  int cj[9];
  #pragma unroll
  for (int j=0;j<9;j++){
    int c = tid + 256*j;
    cj[j] = c;
    float4 wu = (c < KD) ? *(const float4*)&ckw[c*4] : *(const float4*)&cvw[(c-KD)*4];
    w[j][0]=wu.x; w[j][1]=wu.y; w[j][2]=wu.z; w[j][3]=wu.w;
  }
  float p[9][4];
  #pragma unroll
  for (int j=0;j<9;j++){
    p[j][1] = b2f(side[(size_t)(b*3+0)*2304 + cj[j]]);
    p[j][2] = b2f(side[(size_t)(b*3+1)*2304 + cj[j]]);
    p[j][3] = b2f(side[(size_t)(b*3+2)*2304 + cj[j]]);
  }
  int s1 = (base-3>=0) ? seg[base-3] : -1;
  int s2 = (base-2>=0) ? seg[base-2] : -1;
  int s3 = (base-1>=0) ? seg[base-1] : -1;
  int s0;
  for (int rr=0; rr<64; rr++){
    int t = base + rr;
    s0 = s1; s1 = s2; s2 = s3; s3 = seg[t];
    #pragma unroll
    for (int j=0;j<9;j++){
      p[j][0]=p[j][1]; p[j][1]=p[j][2]; p[j][2]=p[j][3];
      int c = cj[j];
      p[j][3] = (c < KD) ? b2f(kpre[(size_t)t*KD + c]) : b2f(vpre[(size_t)t*VD + (c-KD)]);
    }
    bool m0 = (s0==s3), m1 = (s1==s3), m2 = (s2==s3);
    #pragma unroll
    for (int j=0;j<9;j++){
      float val = p[j][3]*w[j][3];
      val += m2 ? p[j][2]*w[j][2] : 0.f;
      val += m1 ? p[j][1]*w[j][1] : 0.f;
      val += m0 ? p[j][0]*w[j][0] : 0.f;
      val = silu(val);
      int c = cj[j];
      if (j < 3){
        float sq = val*val;
        #pragma unroll
        for (int off=1; off<64; off<<=1) sq += __shfl_xor(sq, off);
        float kn = val * rsqrtf(sq + 1e-6f);
        kpre[(size_t)t*KD + c] = f2b(kn);
      } else {
        vpre[(size_t)t*VD + (c-KD)] = f2b(val);
      }
    }
  }
}

// ---------------- q pre-GEMM ----------------
__global__ __launch_bounds__(256,1) void qpre_k(const float* __restrict__ hn_ends,
   const float* __restrict__ Wq, const int* __restrict__ cu, float* __restrict__ qpre)
{
  __shared__ float hrow[H_DIM];
  int tid = threadIdx.x;
  int s = blockIdx.x >> 2, rr = blockIdx.x & 3;
  int t = cu[s+1] - 4 + rr;
  if (t >= 0)
    *(float4*)&hrow[tid*4] = *(const float4*)&hn_ends[(size_t)(s*4+rr)*H_DIM + tid*4];
  __syncthreads();
  for (int j=0;j<3;j++){
    int c = tid + 256*j;
    float acc = 0.f;
    if (t >= 0){
      for (int i0=0; i0<H_DIM; i0++)
        acc = fmaf(hrow[i0], Wq[(size_t)i0*KD + c], acc);
    }
    qpre[(size_t)(s*4+rr)*KD + c] = acc;
  }
}

// ---------------- q conv+silu+l2norm+scale ----------------
__global__ __launch_bounds__(256,1) void qfin_k(const float* __restrict__ qpre,
   const float* __restrict__ cqw, const int* __restrict__ cu, const int* __restrict__ seg,
   float* __restrict__ qf)
{
  int tid = threadIdx.x;
  int s = blockIdx.x;
  int te = cu[s+1]-1;
  for (int j=0;j<3;j++){
    int c = tid + 256*j;
    float4 wu = *(const float4*)&cqw[c*4];
    float wv_[4] = {wu.x, wu.y, wu.z, wu.w};
    float val = 0.f;
    #pragma unroll
    for (int rr=0; rr<4; rr++){
      int t = te - 3 + rr;
      bool ok = (t >= 0) && (seg[t] == s);
      float pv = qpre[(size_t)(s*4+rr)*KD + c];
      val += ok ? pv * wv_[rr] : 0.f;
    }
    val = silu(val);
    float sq = val*val;
    #pragma unroll
    for (int off=1; off<64; off<<=1) sq += __shfl_xor(sq, off);
    qf[(size_t)s*KD + c] = val * rsqrtf(sq + 1e-6f) * 0.125f;
  }
}

// ---------------- G-pass: per (8-block, head) solve coefficients ----------
__global__ __launch_bounds__(64,1) void gq_k(const ushort* __restrict__ kpost,
   const float2* __restrict__ db, const int* __restrict__ cu, float* __restrict__ gbuf)
{
  __shared__ float kls[8][64];
  __shared__ float dls[8];
  __shared__ float bls[8];
  int slot = blockIdx.x, h = blockIdx.y;
  int s=-1, n=0, te=0, L=0, st0=0;
  for (int ss=0; ss<NSEG; ss++){
    int st = cu[ss], en = cu[ss+1];
    int base = (st>>3) + ss;
    int nb = (en - st + 7) >> 3;
    if (slot >= base && slot < base + nb){ s=ss; n=slot-base; te=en-1; L=en-st; st0=st; }
  }
  if (s < 0) return;
  int lane = threadIdx.x;
  int vl = lane>>3, kq = lane&7;
  int j = 8*n + vl;
  bool ok = j < L;
  int t = ok ? (te - j) : st0;
  uint4 kv = *(const uint4*)(kpost + (size_t)t*KD + h*HK + kq*8);
  float f0,f1,f2,f3,f4,f5,f6,f7;
  unpack2(kv.x,f0,f1); unpack2(kv.y,f2,f3); unpack2(kv.z,f4,f5); unpack2(kv.w,f6,f7);
  if (!ok){ f0=0;f1=0;f2=0;f3=0;f4=0;f5=0;f6=0;f7=0; }
  float4 w0; w0.x=f0; w0.y=f1; w0.z=f2; w0.w=f3;
  float4 w1; w1.x=f4; w1.y=f5; w1.z=f6; w1.w=f7;
  *(float4*)&kls[vl][kq*8]   = w0;
  *(float4*)&kls[vl][kq*8+4] = w1;
  if (kq==0){
    float dd = 1.f, bb = 0.f;
    if (ok){ float2 g = db[(size_t)t*NH + h]; dd = g.x; bb = g.y; }
    dls[vl] = dd; bls[vl] = bb;
  }
  __syncthreads();
  float out = 0.f;
  if (lane < 28){
    int i = 1, base = 0;
    while (lane >= base + i){ base += i; i++; }
    int m = lane - base;
    const float4* pm = (const float4*)kls[m];
    const float4* pi = (const float4*)kls[i];
    float g = 0.f;
    #pragma unroll
    for (int d=0; d<16; d++){
      float4 xa = pm[d], xb = pi[d];
      g += xa.x*xb.x + xa.y*xb.y + xa.z*xb.z + xa.w*xb.w;
    }
    float W = 1.f;
    for (int l=m; l<i; l++) W *= dls[l];
    out = W * bls[m] * g;
  } else if (lane < 36){
    int i0 = lane - 28;
    float P = 1.f;
    for (int l=0; l<=i0; l++) P *= dls[l];
    out = P;
  } else if (lane < 44){
    int m = lane - 36;
    float W = 1.f;
    for (int l=m; l<8; l++) W *= dls[l];
    out = W * bls[m];
  } else if (lane < 52){
    out = bls[lane-44];
  }
  if (lane < 52) gbuf[((size_t)slot*NH + h)*52 + lane] = out;
}

// helper: map (slot) -> segment/superblock
__device__ __forceinline__ int sb_locate(const int* cu, int slot,
   int& m, int& start, int& te, int& L, int& gb)
{
  int acc = 0;
  int sfound = -1;
  for (int ss=0; ss<NSEG; ss++){
    int st = cu[ss], en = cu[ss+1];
    int Ls = en - st, nb8 = (Ls+7)>>3, nsb = (nb8+63)>>6;
    if (slot >= acc && slot < acc + nsb){
      sfound = ss; m = slot - acc; start = st; te = en-1; L = Ls; gb = (st>>3)+ss;
    }
    acc += nsb;
  }
  return sfound;
}

// ---------------- msb: superblock composite matrix, column-split + coeff prefetch ----
__global__ __launch_bounds__(512,1) void msb_k(const ushort* __restrict__ kpost,
   const float* __restrict__ gbuf, const int* __restrict__ cu, float* __restrict__ mbuf)
{
  __shared__ float kls[2][8][64];   // [buf][j][dim]
  int slot = blockIdx.x, h = blockIdx.y;
  int m, start, te, L, gb;
  int s = sb_locate(cu, slot, m, start, te, L, gb);
  if (s < 0) return;
  int nb8 = (L+7)>>3;
  int n0 = m*64, n1 = min(nb8, n0+64);
  int tid = threadIdx.x;
  int lane = tid & 63;
  int wv = tid >> 6;
  int cl = lane >> 3, kq = lane & 7;
  int col = wv*8 + cl;
  int d0 = kq*8;
  const ushort* kbase = kpost + h*HK;
  float r0 = (d0+0==col)?1.f:0.f, r1 = (d0+1==col)?1.f:0.f;
  float r2 = (d0+2==col)?1.f:0.f, r3 = (d0+3==col)?1.f:0.f;
  float r4 = (d0+4==col)?1.f:0.f, r5 = (d0+5==col)?1.f:0.f;
  float r6 = (d0+6==col)?1.f:0.f, r7 = (d0+7==col)?1.f:0.f;
  {
    int jj = 8*n0 + wv; int td = (jj<L) ? (te-jj) : start;
    kls[0][wv][lane] = b2f(kbase[(size_t)td*KD + lane]);
  }
  // coeffs for block n0
  const float4* g4 = (const float4*)(gbuf + ((size_t)(gb+n0)*NH + h)*52);
  float4 q0=g4[0], q1=g4[1], q2=g4[2], q3=g4[3], q4=g4[4], q5=g4[5], q6=g4[6],
         q7=g4[7], q8=g4[8], q9=g4[9], q10=g4[10];
  __syncthreads();
  int buf = 0;
  for (int n=n0; n<n1; n++){
    // stage next k block + prefetch next coeffs (loads in flight across compute)
    {
      int nn = (n+1<n1) ? n+1 : n;
      int jj = 8*nn + wv; int td = (jj<L) ? (te-jj) : start;
      kls[buf^1][wv][lane] = b2f(kbase[(size_t)td*KD + lane]);
    }
    int np = (n+1<n1) ? n+1 : n;
    const float4* gn = (const float4*)(gbuf + ((size_t)(gb+np)*NH + h)*52);
    float4 p0=gn[0], p1=gn[1], p2=gn[2], p3=gn[3], p4=gn[4], p5=gn[5], p6=gn[6],
           p7=gn[7], p8=gn[8], p9=gn[9], p10=gn[10];
    // dot partials
    float a0,a1,a2,a3,a4,a5,a6,a7;
#define DOTJ(J, A) { \
    float4 ka = *(const float4*)&kls[buf][J][d0]; \
    float4 kbv = *(const float4*)&kls[buf][J][d0+4]; \
    float xx = ka.x*r0 + ka.y*r1; \
    xx = fmaf(ka.z, r2, xx); xx = fmaf(ka.w, r3, xx); \
    xx = fmaf(kbv.x, r4, xx); xx = fmaf(kbv.y, r5, xx); \
    xx = fmaf(kbv.z, r6, xx); xx = fmaf(kbv.w, r7, xx); \
    A = xx; }
    DOTJ(0,a0) DOTJ(1,a1) DOTJ(2,a2) DOTJ(3,a3)
    DOTJ(4,a4) DOTJ(5,a5) DOTJ(6,a6) DOTJ(7,a7)
#undef DOTJ
    a0 += __shfl_xor(a0,1); a1 += __shfl_xor(a1,1); a2 += __shfl_xor(a2,1); a3 += __shfl_xor(a3,1);
    a4 += __shfl_xor(a4,1); a5 += __shfl_xor(a5,1); a6 += __shfl_xor(a6,1); a7 += __shfl_xor(a7,1);
    a0 += __shfl_xor(a0,2); a1 += __shfl_xor(a1,2); a2 += __shfl_xor(a2,2); a3 += __shfl_xor(a3,2);
    a4 += __shfl_xor(a4,2); a5 += __shfl_xor(a5,2); a6 += __shfl_xor(a6,2); a7 += __shfl_xor(a7,2);
    a0 += __shfl_xor(a0,4); a1 += __shfl_xor(a1,4); a2 += __shfl_xor(a2,4); a3 += __shfl_xor(a3,4);
    a4 += __shfl_xor(a4,4); a5 += __shfl_xor(a5,4); a6 += __shfl_xor(a6,4); a7 += __shfl_xor(a7,4);
    float c0 = a0;
    float c1 = q7.x*a1 - q0.x*c0;
    float c2 = q7.y*a2 - q0.y*c0 - q0.z*c1;
    float c3 = q7.z*a3 - q0.w*c0 - q1.x*c1 - q1.y*c2;
    float c4 = q7.w*a4 - q1.z*c0 - q1.w*c1 - q2.x*c2 - q2.y*c3;
    float c5 = q8.x*a5 - q2.z*c0 - q2.w*c1 - q3.x*c2 - q3.y*c3 - q3.z*c4;
    float c6 = q8.y*a6 - q3.w*c0 - q4.x*c1 - q4.y*c2 - q4.z*c3 - q4.w*c4 - q5.x*c5;
    float c7 = q8.z*a7 - q5.y*c0 - q5.z*c1 - q5.w*c2 - q6.x*c3 - q6.y*c4 - q6.z*c5 - q6.w*c6;
    float g0 = q9.x*c0, g1 = q9.y*c1, g2 = q9.z*c2, g3 = q9.w*c3;
    float g4_= q10.x*c4, g5 = q10.y*c5, g6 = q10.z*c6, g7 = q10.w*c7;
    float P8 = q8.w;
    r0*=P8; r1*=P8; r2*=P8; r3*=P8; r4*=P8; r5*=P8; r6*=P8; r7*=P8;
#define UPDJ(J, G) { \
    float4 ka = *(const float4*)&kls[buf][J][d0]; \
    float4 kbv = *(const float4*)&kls[buf][J][d0+4]; \
    r0 = fmaf(-(G), ka.x, r0); r1 = fmaf(-(G), ka.y, r1); \
    r2 = fmaf(-(G), ka.z, r2); r3 = fmaf(-(G), ka.w, r3); \
    r4 = fmaf(-(G), kbv.x, r4); r5 = fmaf(-(G), kbv.y, r5); \
    r6 = fmaf(-(G), kbv.z, r6); r7 = fmaf(-(G), kbv.w, r7); }
    UPDJ(0,g0) UPDJ(1,g1) UPDJ(2,g2) UPDJ(3,g3)
    UPDJ(4,g4_) UPDJ(5,g5) UPDJ(6,g6) UPDJ(7,g7)
#undef UPDJ
    q0=p0; q1=p1; q2=p2; q3=p3; q4=p4; q5=p5; q6=p6; q7=p7; q8=p8; q9=p9; q10=p10;
    __syncthreads();
    buf ^= 1;
  }
  float* mp = mbuf + ((size_t)slot*NH + h)*4096 + (size_t)col*64 + d0;
  float4 oA; oA.x=r0; oA.y=r1; oA.z=r2; oA.w=r3;
  float4 oB; oB.x=r4; oB.y=r5; oB.z=r6; oB.w=r7;
  *(float4*)&mp[0] = oA;
  *(float4*)&mp[4] = oB;
}

// ---------------- chain: serial r across superblocks (per s,h) ----------------
__global__ __launch_bounds__(64,1) void chain_k(const float* __restrict__ mbuf,
   const float* __restrict__ qf, const int* __restrict__ cu, float* __restrict__ rbuf)
{
  __shared__ float lsr[64];
  int bid = blockIdx.x;
  int s = bid / NH, h = bid % NH;
  int start = cu[s], end = cu[s+1];
  int L = end - start, nb8 = (L+7)>>3, nsb = (nb8+63)>>6;
  int sbase = 0;
  for (int ss=0; ss<s; ss++){
    int Ls = cu[ss+1]-cu[ss];
    sbase += ((((Ls+7)>>3)+63)>>6);
  }
  int lane = threadIdx.x;
  lsr[lane] = qf[(size_t)s*KD + h*HK + lane];
  __syncthreads();
  float r[64];
  #pragma unroll
  for (int i=0;i<64;i++) r[i] = lsr[i];
  for (int mm=0; mm<nsb; mm++){
    int slot = sbase + mm;
    rbuf[((size_t)slot*NH + h)*64 + lane] = lsr[lane];
    if (mm+1 >= nsb) break;
    const float* mb = mbuf + ((size_t)slot*NH + h)*4096 + lane;  // Mt[col][row=lane]
    float y = 0.f;
    #pragma unroll
    for (int col=0; col<64; col++)
      y = fmaf(mb[(size_t)col*64], r[col], y);
    __syncthreads();
    lsr[lane] = y;
    __syncthreads();
    #pragma unroll
    for (int i=0;i<64;i++) r[i] = lsr[i];
  }
}

// ---------------- scan3: per-superblock c' emission, with prefetch ----------
__global__ __launch_bounds__(64,1) void scan3_k(const ushort* __restrict__ kpost,
   const float* __restrict__ gbuf, const float* __restrict__ rbuf,
   const int* __restrict__ cu, float* __restrict__ cbuf)
{
  int slot = blockIdx.x, h = blockIdx.y;
  int m, start, te, L, gb;
  int s = sb_locate(cu, slot, m, start, te, L, gb);
  if (s < 0) return;
  int nb8 = (L+7)>>3;
  int n0 = m*64, n1 = min(nb8, n0+64);
  int lane = threadIdx.x;
  int vl = lane>>3, kq = lane&7;
  const float* rp = rbuf + ((size_t)slot*NH + h)*64 + kq*8;
  float4 rA = *(const float4*)rp;
  float4 rB = *(const float4*)(rp+4);
  float r0=rA.x, r1=rA.y, r2=rA.z, r3=rA.w, r4=rB.x, r5=rB.y, r6=rB.z, r7=rB.w;
  const ushort* kb = kpost + h*HK + kq*8;
  // block n0 coeffs + kd
  const float4* g4 = (const float4*)(gbuf + ((size_t)(gb+n0)*NH + h)*52);
  float4 q0=g4[0], q1=g4[1], q2=g4[2], q3=g4[3], q4=g4[4], q5=g4[5], q6=g4[6],
         q7=g4[7], q8=g4[8], q9=g4[9], q10=g4[10], q11=g4[11], q12=g4[12];
  uint4 kd;
  {
    int jj = 8*n0 + vl; bool ok = jj < L; int td = ok ? te - jj : start;
    kd = *(const uint4*)(kb + (size_t)td*KD);
    if (!ok){ kd.x=0; kd.y=0; kd.z=0; kd.w=0; }
  }
  for (int n=n0; n<n1; n++){
    // prefetch next coeffs + kd
    int np = (n+1<n1) ? n+1 : n;
    const float4* gn = (const float4*)(gbuf + ((size_t)(gb+np)*NH + h)*52);
    float4 p0=gn[0], p1=gn[1], p2=gn[2], p3=gn[3], p4=gn[4], p5=gn[5], p6=gn[6],
           p7=gn[7], p8=gn[8], p9=gn[9], p10=gn[10], p11=gn[11], p12=gn[12];
    uint4 kdn; bool okn;
    {
      int jj = 8*np + vl; okn = jj < L; int td = okn ? te - jj : start;
      kdn = *(const uint4*)(kb + (size_t)td*KD);
    }
    int jj = 8*n + vl;
    int tb = te - 8*n;
    int t0c = max(tb-0, start), t1c = max(tb-1, start), t2c = max(tb-2, start), t3c = max(tb-3, start);
    int t4c = max(tb-4, start), t5c = max(tb-5, start), t6c = max(tb-6, start), t7c = max(tb-7, start);
    uint4 km0 = *(const uint4*)(kb + (size_t)t0c*KD);
    uint4 km1 = *(const uint4*)(kb + (size_t)t1c*KD);
    uint4 km2 = *(const uint4*)(kb + (size_t)t2c*KD);
    uint4 km3 = *(const uint4*)(kb + (size_t)t3c*KD);
    uint4 km4 = *(const uint4*)(kb + (size_t)t4c*KD);
    uint4 km5 = *(const uint4*)(kb + (size_t)t5c*KD);
    uint4 km6 = *(const uint4*)(kb + (size_t)t6c*KD);
    uint4 km7 = *(const uint4*)(kb + (size_t)t7c*KD);
    float kk0,kk1,kk2,kk3,kk4,kk5,kk6,kk7;
    unpack2(kd.x, kk0, kk1); unpack2(kd.y, kk2, kk3);
    unpack2(kd.z, kk4, kk5); unpack2(kd.w, kk6, kk7);
    float pa = r0*kk0, pb = r1*kk1;
    pa = fmaf(r2, kk2, pa); pb = fmaf(r3, kk3, pb);
    pa = fmaf(r4, kk4, pa); pb = fmaf(r5, kk5, pb);
    pa = fmaf(r6, kk6, pa); pb = fmaf(r7, kk7, pb);
    float part = pa + pb;
    part += __shfl_xor(part, 1); part += __shfl_xor(part, 2); part += __shfl_xor(part, 4);
    float a0 = __shfl(part, 0*8+kq), a1 = __shfl(part, 1*8+kq);
    float a2 = __shfl(part, 2*8+kq), a3 = __shfl(part, 3*8+kq);
    float a4 = __shfl(part, 4*8+kq), a5 = __shfl(part, 5*8+kq);
    float a6 = __shfl(part, 6*8+kq), a7 = __shfl(part, 7*8+kq);
    float c0 = a0;
    float c1 = q7.x*a1 - q0.x*c0;
    float c2 = q7.y*a2 - q0.y*c0 - q0.z*c1;
    float c3 = q7.z*a3 - q0.w*c0 - q1.x*c1 - q1.y*c2;
    float c4 = q7.w*a4 - q1.z*c0 - q1.w*c1 - q2.x*c2 - q2.y*c3;
    float c5 = q8.x*a5 - q2.z*c0 - q2.w*c1 - q3.x*c2 - q3.y*c3 - q3.z*c4;
    float c6 = q8.y*a6 - q3.w*c0 - q4.x*c1 - q4.y*c2 - q4.z*c3 - q4.w*c4 - q5.x*c5;
    float c7 = q8.z*a7 - q5.y*c0 - q5.z*c1 - q5.w*c2 - q6.x*c3 - q6.y*c4 - q6.z*c5 - q6.w*c6;
    {
      float cw = vl==0?c0: vl==1?c1: vl==2?c2: vl==3?c3: vl==4?c4: vl==5?c5: vl==6?c6: c7;
      float bw = vl==0?q11.x: vl==1?q11.y: vl==2?q11.z: vl==3?q11.w:
                 vl==4?q12.x: vl==5?q12.y: vl==6?q12.z: q12.w;
      if (kq == 0 && jj < L) cbuf[(size_t)(te-jj)*NH + h] = bw*cw;
    }
    float g0 = q9.x*c0, g1 = q9.y*c1, g2 = q9.z*c2, g3 = q9.w*c3;
    float g4_= q10.x*c4, g5 = q10.y*c5, g6 = q10.z*c6, g7 = q10.w*c7;
    float P8 = q8.w;
    r0*=P8; r1*=P8; r2*=P8; r3*=P8; r4*=P8; r5*=P8; r6*=P8; r7*=P8;
    float e0,e1,e2,e3,e4,e5,e6,e7;
#define UPD(KM,GM) \
    unpack2(KM.x,e0,e1); unpack2(KM.y,e2,e3); unpack2(KM.z,e4,e5); unpack2(KM.w,e6,e7); \
    r0 = fmaf(-GM, e0, r0); r1 = fmaf(-GM, e1, r1); r2 = fmaf(-GM, e2, r2); r3 = fmaf(-GM, e3, r3); \
    r4 = fmaf(-GM, e4, r4); r5 = fmaf(-GM, e5, r5); r6 = fmaf(-GM, e6, r6); r7 = fmaf(-GM, e7, r7);
    UPD(km0,g0) UPD(km1,g1) UPD(km2,g2) UPD(km3,g3)
    UPD(km4,g4_) UPD(km5,g5) UPD(km6,g6) UPD(km7,g7)
#undef UPD
    q0=p0; q1=p1; q2=p2; q3=p3; q4=p4; q5=p5; q6=p6; q7=p7; q8=p8; q9=p9; q10=p10; q11=p11; q12=p12;
    if (!okn){ kdn.x=0; kdn.y=0; kdn.z=0; kdn.w=0; }
    kd = kdn;
  }
}

// ---------------- zero obuf ----------------
__global__ void zerok(float* __restrict__ p, int n){
  int i = blockIdx.x*256 + threadIdx.x;
  if (i < n) p[i] = 0.f;
}

// ---------------- o gemv, t-chunked with atomics ----------------
__global__ __launch_bounds__(128,1) void ogemv2_k(const ushort* __restrict__ vpost,
   const float* __restrict__ cbuf, const int* __restrict__ cu, float* __restrict__ obuf)
{
  int bid = blockIdx.x;
  int ch = bid % OCH;
  int sh = bid / OCH;
  int s = sh / NH, h = sh % NH;
  int start = cu[s], end = cu[s+1];
  int L = end - start;
  int clen = (L + OCH - 1) / OCH;
  int t0 = start + ch*clen;
  int t1 = min(end, t0 + clen);
  if (t0 >= t1) return;
  int v = threadIdx.x;
  const ushort* vp = vpost + h*HV + v;
  const float* cp = cbuf + h;
  float o0=0,o1=0,o2=0,o3=0,o4=0,o5=0,o6=0,o7=0;
  int t = t0;
  for (; t+8 <= t1; t+=8){
    o0 = fmaf(cp[(size_t)(t+0)*NH], b2f(vp[(size_t)(t+0)*VD]), o0);
    o1 = fmaf(cp[(size_t)(t+1)*NH], b2f(vp[(size_t)(t+1)*VD]), o1);
    o2 = fmaf(cp[(size_t)(t+2)*NH], b2f(vp[(size_t)(t+2)*VD]), o2);
    o3 = fmaf(cp[(size_t)(t+3)*NH], b2f(vp[(size_t)(t+3)*VD]), o3);
    o4 = fmaf(cp[(size_t)(t+4)*NH], b2f(vp[(size_t)(t+4)*VD]), o4);
    o5 = fmaf(cp[(size_t)(t+5)*NH], b2f(vp[(size_t)(t+5)*VD]), o5);
    o6 = fmaf(cp[(size_t)(t+6)*NH], b2f(vp[(size_t)(t+6)*VD]), o6);
    o7 = fmaf(cp[(size_t)(t+7)*NH], b2f(vp[(size_t)(t+7)*VD]), o7);
  }
  for (; t<t1; t++) o0 = fmaf(cp[(size_t)t*NH], b2f(vp[(size_t)t*VD]), o0);
  float o = ((o0+o1)+(o2+o3)) + ((o4+o5)+(o6+o7));
  atomicAdd(&obuf[(size_t)s*VD + h*HV + v], o);
}

// ---------------- o-norm + gate + silu ----------------
__global__ __launch_bounds__(256,1) void gate_k(const float* __restrict__ obuf,
   const float* __restrict__ hn_ends, const float* __restrict__ Wg,
   const float* __restrict__ onw, const int* __restrict__ cu, float* __restrict__ og)
{
  __shared__ float red[4];
  __shared__ float hrow[H_DIM];
  int tid = threadIdx.x;
  int s = blockIdx.x / 6, ch = blockIdx.x % 6;
  int cc = ch*256 + tid;
  *(float4*)&hrow[tid*4] = *(const float4*)&hn_ends[(size_t)(s*4+3)*H_DIM + tid*4];
  float o = obuf[(size_t)s*VD + cc];
  float sq = o*o;
  #pragma unroll
  for (int off=1; off<64; off<<=1) sq += __shfl_xor(sq, off);
  int wv = tid>>6, lane = tid&63;
  if (lane==0) red[wv] = sq;
  __syncthreads();
  float ssum = (tid<128) ? (red[0]+red[1]) : (red[2]+red[3]);
  float onr = o * rsqrtf(ssum*(1.f/128.f) + 1e-5f) * onw[cc & 127];
  float acc = 0.f;
  for (int i0=0;i0<H_DIM;i0++)
    acc = fmaf(hrow[i0], Wg[(size_t)i0*VD + cc], acc);
  og[(size_t)s*VD + cc] = onr * acc * sigm(acc);
}

// ---------------- final projection + head ----------------
__global__ __launch_bounds__(256,1) void final_k(const float* __restrict__ og,
   const float* __restrict__ Wo, const float* __restrict__ h_end,
   const float* __restrict__ W_head, const float* __restrict__ b_head,
   float* __restrict__ out)
{
  __shared__ float ogs[VD];
  __shared__ float redp[4];
  int tid = threadIdx.x;
  int s = blockIdx.x;
  for (int j=tid; j<VD; j+=256) ogs[j] = og[(size_t)s*VD + j];
  __syncthreads();
  int c0 = tid*4;
  float4 hh4 = *(const float4*)&h_end[(size_t)s*H_DIM + c0];
  float acc0 = hh4.x, acc1 = hh4.y, acc2 = hh4.z, acc3 = hh4.w;
  for (int j=0;j<VD;j++){
    float ov = ogs[j];
    float4 wo = *(const float4*)&Wo[(size_t)j*H_DIM + c0];
    acc0 = fmaf(ov,wo.x,acc0); acc1 = fmaf(ov,wo.y,acc1);
    acc2 = fmaf(ov,wo.z,acc2); acc3 = fmaf(ov,wo.w,acc3);
  }
  float4 wh = *(const float4*)&W_head[c0];
  float p = acc0*wh.x + acc1*wh.y + acc2*wh.z + acc3*wh.w;
  #pragma unroll
  for (int off=1; off<64; off<<=1) p += __shfl_xor(p, off);
  int wv = tid>>6, lane = tid&63;
  if (lane==0) redp[wv] = p;
  __syncthreads();
  if (tid==0) out[s] = redp[0]+redp[1]+redp[2]+redp[3] + b_head[0];
}

extern "C" void kernel_launch(void* const* d_in, const int* in_sizes, int n_in,
                              void* d_out, int out_size, void* d_ws, size_t ws_size,
                              hipStream_t stream)
{
  const float* x      = (const float*)d_in[0];
  const int*   cu     = (const int*)  d_in[1];
  const int*   atype  = (const int*)  d_in[2];
  const float* ac_tab = (const float*)d_in[3];
  const float* W_in   = (const float*)d_in[4];
  const float* b_in   = (const float*)d_in[5];
  const float* norm_w = (const float*)d_in[6];
  const float* Wq     = (const float*)d_in[7];
  const float* Wk     = (const float*)d_in[8];
  const float* Wv     = (const float*)d_in[9];
  const float* cqw    = (const float*)d_in[10];
  const float* ckw    = (const float*)d_in[11];
  const float* cvw    = (const float*)d_in[12];
  const float* Wb     = (const float*)d_in[13];
  const float* Wa     = (const float*)d_in[14];
  const float* A_log  = (const float*)d_in[15];
  const float* dt_b   = (const float*)d_in[16];
  const float* Wg     = (const float*)d_in[17];
  const float* onw    = (const float*)d_in[18];
  const float* Wo     = (const float*)d_in[19];
  const float* W_head = (const float*)d_in[20];
  const float* b_head = (const float*)d_in[21];
  float* out = (float*)d_out;

  // ---- workspace (~211 MiB peak) ----
  char* w = (char*)d_ws;
  int*    seg     = (int*)w;     w += (size_t)T_TOK*4;
  float*  h_end   = (float*)w;   w += (size_t)NSEG*H_DIM*4;
  float*  hn_ends = (float*)w;   w += (size_t)NSEG*4*H_DIM*4;
  float*  qpre    = (float*)w;   w += (size_t)NSEG*4*KD*4;
  float*  qf      = (float*)w;   w += (size_t)NSEG*KD*4;
  float*  obuf    = (float*)w;   w += (size_t)NSEG*VD*4;
  float*  og      = (float*)w;   w += (size_t)NSEG*VD*4;
  float2* db      = (float2*)w;  w += (size_t)T_TOK*NH*8;
  float*  ba      = (float*)w;   w += (size_t)T_TOK*32*4;
  ushort* wt      = (ushort*)w;  w += (size_t)NCOL*H_DIM*2;
  ushort* side    = (ushort*)w;  w += (size_t)(T_TOK/64)*3*2304*2;
  float*  cbuf    = (float*)w;   w += (size_t)T_TOK*NH*4;
  float*  gbuf    = (float*)w;   w += (size_t)NSLOT*NH*52*4;
  float*  mbuf    = (float*)w;   w += (size_t)MAXSB*NH*4096*4;
  float*  rbuf    = (float*)w;   w += (size_t)MAXSB*NH*64*4;
  ushort* hn_c    = (ushort*)w;  w += (size_t)CHUNK_M*H_DIM*2;
  ushort* kpre    = (ushort*)w;  w += (size_t)T_TOK*KD*2;
  ushort* vpre    = (ushort*)w;  w += (size_t)T_TOK*VD*2;

  hipLaunchKernelGGL(segk,     dim3(T_TOK/256),        dim3(256), 0, stream, cu, seg);
  hipLaunchKernelGGL(build_wt, dim3((NCOL*H_DIM)/256), dim3(256), 0, stream, Wk, Wv, Wb, Wa, wt);
  hipLaunchKernelGGL(zerok,    dim3((NSEG*VD+255)/256),dim3(256), 0, stream, obuf, NSEG*VD);
  for (int c = 0; c < T_TOK/CHUNK_M; c++){
    int row_base = c*CHUNK_M;
    hipLaunchKernelGGL(stage_a,  dim3(CHUNK_M/8), dim3(256), 0, stream,
                       x, atype, ac_tab, W_in, b_in, norm_w, seg, row_base, hn_c, h_end, hn_ends);
    hipLaunchKernelGGL(gemm_bf16, dim3((CHUNK_M/128)*(NCOL/128)), dim3(256), 0, stream,
                       hn_c, wt, row_base, kpre, vpre, ba);
  }
  hipLaunchKernelGGL(dbk,      dim3((T_TOK*NH)/256),   dim3(256), 0, stream, ba, A_log, dt_b, db);
  hipLaunchKernelGGL(side_k,   dim3(T_TOK/64),         dim3(256), 0, stream, kpre, vpre, side);
  hipLaunchKernelGGL(conv_ip,  dim3(T_TOK/64),         dim3(256), 0, stream, kpre, vpre, side, seg, ckw, cvw);
  hipLaunchKernelGGL(qpre_k,   dim3(NSEG*4),           dim3(256), 0, stream, hn_ends, Wq, cu, qpre);
  hipLaunchKernelGGL(qfin_k,   dim3(NSEG),             dim3(256), 0, stream, qpre, cqw, cu, seg, qf);
  hipLaunchKernelGGL(gq_k,     dim3(NSLOT, NH),        dim3(64),  0, stream, kpre, db, cu, gbuf);
  hipLaunchKernelGGL(msb_k,    dim3(MAXSB, NH),        dim3(512), 0, stream, kpre, gbuf, cu, mbuf);
  hipLaunchKernelGGL(chain_k,  dim3(NSEG*NH),          dim3(64),  0, stream, mbuf, qf, cu, rbuf);
  hipLaunchKernelGGL(scan3_k,  dim3(MAXSB, NH),        dim3(64),  0, stream, kpre, gbuf, rbuf, cu, cbuf);
  hipLaunchKernelGGL(ogemv2_k, dim3(NSEG*NH*OCH),      dim3(128), 0, stream, vpre, cbuf, cu, obuf);
  hipLaunchKernelGGL(gate_k,   dim3(NSEG*6),           dim3(256), 0, stream, obuf, hn_ends, Wg, onw, cu, og);
  hipLaunchKernelGGL(final_k,  dim3(NSEG),             dim3(256), 0, stream, og, Wo, h_end, W_head, b_head, out);
}

// Round 11
// 1552.764 us; speedup vs baseline: 1.0890x; 1.0890x over previous
//
#include <hip/hip_runtime.h>
#include <stdint.h>

#define T_TOK 32768
#define H_DIM 1024
#define NH    12
#define HK    64
#define HV    128
#define KD    768
#define VD    1536
#define NSEG  16
#define NCOL  2432
#define FEAT  48
#define CHUNK_M 4096
#define NSLOT (T_TOK/8 + 32)
#define MAXSB 96
#define OCH   8

typedef unsigned int uint;
typedef unsigned short ushort;

typedef short bf16x8_t __attribute__((ext_vector_type(8)));
typedef float f32x4_t  __attribute__((ext_vector_type(4)));

__device__ __forceinline__ ushort f2b(float f){
  uint u = __float_as_uint(f);
  u += 0x7fffu + ((u>>16)&1u);
  return (ushort)(u>>16);
}
__device__ __forceinline__ float b2f(ushort u){ return __uint_as_float(((uint)u)<<16); }
__device__ __forceinline__ void unpack2(uint u, float&a, float&b){
  a = __uint_as_float(u<<16); b = __uint_as_float(u & 0xffff0000u);
}
__device__ __forceinline__ float sigm(float x){ return 1.f/(1.f + __expf(-x)); }
__device__ __forceinline__ float silu(float x){ return x * sigm(x); }

// async global->LDS, 16B per lane; LDS dest = wave-uniform base + lane*16
__device__ __forceinline__ void gl16(const ushort* g, ushort* l){
  __builtin_amdgcn_global_load_lds(
    (const __attribute__((address_space(1))) uint*)g,
    (__attribute__((address_space(3))) uint*)l, 16, 0, 0);
}

// ---------------- seg_id ----------------
__global__ void segk(const int* __restrict__ cu, int* __restrict__ seg){
  int t = blockIdx.x*256 + threadIdx.x;
  if (t >= T_TOK) return;
  int s = 0;
  #pragma unroll
  for (int i=1;i<=NSEG;i++) s += (cu[i] <= t) ? 1 : 0;
  seg[t] = s;
}

// ---------------- stage A ----------------
__global__ __launch_bounds__(256,1) void stage_a(const float* __restrict__ x,
   const int* __restrict__ atype, const float* __restrict__ ac_table,
   const float* __restrict__ W_in, const float* __restrict__ b_in,
   const float* __restrict__ norm_w, const int* __restrict__ seg, int row_base,
   ushort* __restrict__ hn, float* __restrict__ h_end, float* __restrict__ hn_ends)
{
  __shared__ float feat[8][FEAT];
  __shared__ float hbuf[8][H_DIM];
  __shared__ float red[8];
  int tid = threadIdx.x;
  int base = row_base + blockIdx.x*8;
  int lbase = blockIdx.x*8;
  if (tid < 8) red[tid] = 0.f;
  for (int idx=tid; idx<8*FEAT; idx+=256){
    int rr = idx / FEAT, i = idx % FEAT;
    int t = base + rr;
    float v;
    if (i < 16) v = x[t*16 + i];
    else { int s = seg[t]; int a = atype[s]; v = ac_table[a*32 + (i-16)]; }
    feat[rr][i] = v;
  }
  __syncthreads();
  int c0 = tid*4;
  int lane = tid & 63;
  float4 bi = *(const float4*)&b_in[c0];
  for (int rc=0; rc<2; rc++){
    float acc[4][4];
    #pragma unroll
    for (int r4=0;r4<4;r4++){ acc[r4][0]=bi.x; acc[r4][1]=bi.y; acc[r4][2]=bi.z; acc[r4][3]=bi.w; }
    for (int i=0;i<FEAT;i++){
      float4 wu = *(const float4*)&W_in[i*H_DIM + c0];
      #pragma unroll
      for (int r4=0;r4<4;r4++){
        float f = feat[rc*4+r4][i];
        acc[r4][0] = fmaf(f,wu.x,acc[r4][0]);
        acc[r4][1] = fmaf(f,wu.y,acc[r4][1]);
        acc[r4][2] = fmaf(f,wu.z,acc[r4][2]);
        acc[r4][3] = fmaf(f,wu.w,acc[r4][3]);
      }
    }
    #pragma unroll
    for (int r4=0;r4<4;r4++){
      int rr = rc*4+r4;
      float sq = acc[r4][0]*acc[r4][0] + acc[r4][1]*acc[r4][1]
               + acc[r4][2]*acc[r4][2] + acc[r4][3]*acc[r4][3];
      #pragma unroll
      for (int off=1; off<64; off<<=1) sq += __shfl_xor(sq, off);
      if (lane==0) atomicAdd(&red[rr], sq);
      hbuf[rr][c0]=acc[r4][0]; hbuf[rr][c0+1]=acc[r4][1];
      hbuf[rr][c0+2]=acc[r4][2]; hbuf[rr][c0+3]=acc[r4][3];
    }
  }
  __syncthreads();
  float4 nw = *(const float4*)&norm_w[c0];
  for (int rr=0; rr<8; rr++){
    int t = base + rr;
    float sc = rsqrtf(red[rr]*(1.f/1024.f) + 1e-6f);
    float h0=hbuf[rr][c0], h1=hbuf[rr][c0+1], h2=hbuf[rr][c0+2], h3=hbuf[rr][c0+3];
    float n0=h0*sc*(1.f+nw.x), n1=h1*sc*(1.f+nw.y);
    float n2=h2*sc*(1.f+nw.z), n3=h3*sc*(1.f+nw.w);
    uint2 ov; ov.x = (uint)f2b(n0) | ((uint)f2b(n1)<<16);
    ov.y = (uint)f2b(n2) | ((uint)f2b(n3)<<16);
    *(uint2*)&hn[(size_t)(lbase+rr)*H_DIM + c0] = ov;
    int sgt = seg[t];
    bool isend = (t == T_TOK-1) || (seg[t+1] != sgt);
    if (isend){
      float* he = h_end + (size_t)sgt*H_DIM + c0;
      he[0]=h0; he[1]=h1; he[2]=h2; he[3]=h3;
    }
    #pragma unroll
    for (int d=0; d<4; d++){
      int td = t + d;
      if (td < T_TOK && seg[td] == sgt){
        bool end2 = (td == T_TOK-1) || (seg[td+1] != sgt);
        if (end2){
          float* hd = hn_ends + ((size_t)sgt*4 + (3-d))*H_DIM + c0;
          hd[0]=n0; hd[1]=n1; hd[2]=n2; hd[3]=n3;
        }
      }
    }
  }
}

// ---------------- build fused transposed weight ----------------
__global__ void build_wt(const float* __restrict__ Wk, const float* __restrict__ Wv,
                         const float* __restrict__ Wb, const float* __restrict__ Wa,
                         ushort* __restrict__ wt)
{
  int idx = blockIdx.x*256 + threadIdx.x;
  int n = idx >> 10, k = idx & 1023;
  float v;
  if      (n < 768)  v = Wk[k*768 + n];
  else if (n < 2304) v = Wv[k*1536 + (n-768)];
  else if (n < 2316) v = Wb[k*12 + (n-2304)];
  else if (n < 2328) v = Wa[k*12 + (n-2316)];
  else               v = 0.f;
  wt[idx] = f2b(v);
}

// ---------------- chunked MFMA GEMM, double-buffered global_load_lds staging ----------
__global__ __launch_bounds__(256,1) void gemm_bf16(const ushort* __restrict__ A,
    const ushort* __restrict__ Bt, int row_base,
    ushort* __restrict__ kpre, ushort* __restrict__ vpre, float* __restrict__ ba)
{
  const int K = H_DIM;
  __shared__ ushort As[2][4096];
  __shared__ ushort Bs[2][4096];
  int tid = threadIdx.x;
  const int ntile = NCOL >> 7;
  int mt = blockIdx.x / ntile, nt = blockIdx.x % ntile;
  int m0 = mt<<7, n0 = nt<<7;
  int lane = tid & 63;
  int wv = tid >> 6;
  // staging map: lane l of wave w covers row w*16 + (l>>2), cols (l&3)*8..+8
  int rS = wv*16 + (lane>>2);
  int cS = (lane&3)<<3;
  const ushort* pa0 = A  + (size_t)(m0 + rS)*K + cS;
  const ushort* pa1 = A  + (size_t)(m0 + rS + 64)*K + cS;
  const ushort* pb0 = Bt + (size_t)(n0 + rS)*K + cS;
  const ushort* pb1 = Bt + (size_t)(n0 + rS + 64)*K + cS;
  int wm = (wv>>1)<<6, wn = (wv&1)<<6;
  int mloc = lane & 15, q8 = (lane>>4)<<3;
  f32x4_t acc[4][4];
  f32x4_t zero = {0.f,0.f,0.f,0.f};
  #pragma unroll
  for (int i=0;i<4;i++)
    #pragma unroll
    for (int j=0;j<4;j++) acc[i][j] = zero;
  // prologue: stage tile 0 into buffer 0
  gl16(pa0, &As[0][wv*512]);
  gl16(pa1, &As[0][2048 + wv*512]);
  gl16(pb0, &Bs[0][wv*512]);
  gl16(pb1, &Bs[0][2048 + wv*512]);
  int buf = 0;
  for (int kk=0; kk<K; kk+=32){
    __syncthreads();   // drains vmcnt (tile kk ready) + protects buf^1 overwrite
    if (kk + 32 < K){  // issue next tile AFTER barrier -> overlaps with compute below
      gl16(pa0 + kk + 32, &As[buf^1][wv*512]);
      gl16(pa1 + kk + 32, &As[buf^1][2048 + wv*512]);
      gl16(pb0 + kk + 32, &Bs[buf^1][wv*512]);
      gl16(pb1 + kk + 32, &Bs[buf^1][2048 + wv*512]);
    }
    bf16x8_t af[4], bfr[4];
    #pragma unroll
    for (int i=0;i<4;i++){
      af[i]  = *(const bf16x8_t*)&As[buf][(wm + i*16 + mloc)*32 + q8];
      bfr[i] = *(const bf16x8_t*)&Bs[buf][(wn + i*16 + mloc)*32 + q8];
    }
    #pragma unroll
    for (int i=0;i<4;i++)
      #pragma unroll
      for (int j=0;j<4;j++)
        acc[i][j] = __builtin_amdgcn_mfma_f32_16x16x32_bf16(af[i], bfr[j], acc[i][j], 0,0,0);
    buf ^= 1;
  }
  int rq = (lane>>4)<<2;
  if (nt < 18){
    ushort* dst; int nstr, cbase;
    if (nt < 6) { dst = kpre; nstr = KD; cbase = n0; }
    else        { dst = vpre; nstr = VD; cbase = n0 - KD; }
    #pragma unroll
    for (int i=0;i<4;i++){
      #pragma unroll
      for (int j=0;j<4;j++){
        int colg = cbase + wn + j*16 + mloc;
        #pragma unroll
        for (int rg=0; rg<4; rg++){
          int rowg = row_base + m0 + wm + i*16 + rq + rg;
          dst[(size_t)rowg*nstr + colg] = f2b(acc[i][j][rg]);
        }
      }
    }
  } else {
    #pragma unroll
    for (int i=0;i<4;i++){
      #pragma unroll
      for (int j=0;j<4;j++){
        int cl = wn + j*16 + mloc;
        if (cl >= 24) continue;
        #pragma unroll
        for (int rg=0; rg<4; rg++){
          int rowg = row_base + m0 + wm + i*16 + rq + rg;
          ba[(size_t)rowg*32 + cl] = acc[i][j][rg];
        }
      }
    }
  }
}

// ---------------- decay/beta ----------------
__global__ void dbk(const float* __restrict__ ba, const float* __restrict__ A_log,
                    const float* __restrict__ dt_bias, float2* __restrict__ db)
{
  int idx = blockIdx.x*256 + threadIdx.x;
  if (idx >= T_TOK*NH) return;
  int t = idx / NH, hh = idx % NH;
  float bp = ba[(size_t)t*32 + hh];
  float ap = ba[(size_t)t*32 + 12 + hh] + dt_bias[hh];
  float beta = sigm(bp);
  float sp = (ap > 20.f) ? ap : log1pf(__expf(ap));
  float dec = __expf(-__expf(A_log[hh]) * sp);
  float2 o; o.x = dec; o.y = beta;
  db[idx] = o;
}

// ---------------- side rows for conv ----------------
__global__ void side_k(const ushort* __restrict__ kpre, const ushort* __restrict__ vpre,
                       ushort* __restrict__ side)
{
  int b = blockIdx.x;
  int base = b*64;
  for (int idx=threadIdx.x; idx<3*2304; idx+=256){
    int jrow = idx / 2304, c = idx % 2304;
    int t0 = base - 3 + jrow;
    ushort v = 0;
    if (t0 >= 0)
      v = (c < KD) ? kpre[(size_t)t0*KD + c] : vpre[(size_t)t0*VD + (c-KD)];
    side[(size_t)(b*3 + jrow)*2304 + c] = v;
  }
}

// ---------------- conv+silu (+l2norm k) in place ----------------
__global__ __launch_bounds__(256,1) void conv_ip(ushort* __restrict__ kpre,
   ushort* __restrict__ vpre, const ushort* __restrict__ side,
   const int* __restrict__ seg, const float* __restrict__ ckw, const float* __restrict__ cvw)
{
  int tid = threadIdx.x;
  int b = blockIdx.x;
  int base = b * 64;
  float w[9][4];
  int cj[9];
  #pragma unroll
  for (int j=0;j<9;j++){
    int c = tid + 256*j;
    cj[j] = c;
    float4 wu = (c < KD) ? *(const float4*)&ckw[c*4] : *(const float4*)&cvw[(c-KD)*4];
    w[j][0]=wu.x; w[j][1]=wu.y; w[j][2]=wu.z; w[j][3]=wu.w;
  }
  float p[9][4];
  #pragma unroll
  for (int j=0;j<9;j++){
    p[j][1] = b2f(side[(size_t)(b*3+0)*2304 + cj[j]]);
    p[j][2] = b2f(side[(size_t)(b*3+1)*2304 + cj[j]]);
    p[j][3] = b2f(side[(size_t)(b*3+2)*2304 + cj[j]]);
  }
  int s1 = (base-3>=0) ? seg[base-3] : -1;
  int s2 = (base-2>=0) ? seg[base-2] : -1;
  int s3 = (base-1>=0) ? seg[base-1] : -1;
  int s0;
  for (int rr=0; rr<64; rr++){
    int t = base + rr;
    s0 = s1; s1 = s2; s2 = s3; s3 = seg[t];
    #pragma unroll
    for (int j=0;j<9;j++){
      p[j][0]=p[j][1]; p[j][1]=p[j][2]; p[j][2]=p[j][3];
      int c = cj[j];
      p[j][3] = (c < KD) ? b2f(kpre[(size_t)t*KD + c]) : b2f(vpre[(size_t)t*VD + (c-KD)]);
    }
    bool m0 = (s0==s3), m1 = (s1==s3), m2 = (s2==s3);
    #pragma unroll
    for (int j=0;j<9;j++){
      float val = p[j][3]*w[j][3];
      val += m2 ? p[j][2]*w[j][2] : 0.f;
      val += m1 ? p[j][1]*w[j][1] : 0.f;
      val += m0 ? p[j][0]*w[j][0] : 0.f;
      val = silu(val);
      int c = cj[j];
      if (j < 3){
        float sq = val*val;
        #pragma unroll
        for (int off=1; off<64; off<<=1) sq += __shfl_xor(sq, off);
        float kn = val * rsqrtf(sq + 1e-6f);
        kpre[(size_t)t*KD + c] = f2b(kn);
      } else {
        vpre[(size_t)t*VD + (c-KD)] = f2b(val);
      }
    }
  }
}

// ---------------- q pre-GEMM ----------------
__global__ __launch_bounds__(256,1) void qpre_k(const float* __restrict__ hn_ends,
   const float* __restrict__ Wq, const int* __restrict__ cu, float* __restrict__ qpre)
{
  __shared__ float hrow[H_DIM];
  int tid = threadIdx.x;
  int s = blockIdx.x >> 2, rr = blockIdx.x & 3;
  int t = cu[s+1] - 4 + rr;
  if (t >= 0)
    *(float4*)&hrow[tid*4] = *(const float4*)&hn_ends[(size_t)(s*4+rr)*H_DIM + tid*4];
  __syncthreads();
  for (int j=0;j<3;j++){
    int c = tid + 256*j;
    float acc = 0.f;
    if (t >= 0){
      for (int i0=0; i0<H_DIM; i0++)
        acc = fmaf(hrow[i0], Wq[(size_t)i0*KD + c], acc);
    }
    qpre[(size_t)(s*4+rr)*KD + c] = acc;
  }
}

// ---------------- q conv+silu+l2norm+scale ----------------
__global__ __launch_bounds__(256,1) void qfin_k(const float* __restrict__ qpre,
   const float* __restrict__ cqw, const int* __restrict__ cu, const int* __restrict__ seg,
   float* __restrict__ qf)
{
  int tid = threadIdx.x;
  int s = blockIdx.x;
  int te = cu[s+1]-1;
  for (int j=0;j<3;j++){
    int c = tid + 256*j;
    float4 wu = *(const float4*)&cqw[c*4];
    float wv_[4] = {wu.x, wu.y, wu.z, wu.w};
    float val = 0.f;
    #pragma unroll
    for (int rr=0; rr<4; rr++){
      int t = te - 3 + rr;
      bool ok = (t >= 0) && (seg[t] == s);
      float pv = qpre[(size_t)(s*4+rr)*KD + c];
      val += ok ? pv * wv_[rr] : 0.f;
    }
    val = silu(val);
    float sq = val*val;
    #pragma unroll
    for (int off=1; off<64; off<<=1) sq += __shfl_xor(sq, off);
    qf[(size_t)s*KD + c] = val * rsqrtf(sq + 1e-6f) * 0.125f;
  }
}

// ---------------- G-pass: per (8-block, head) solve coefficients ----------
__global__ __launch_bounds__(64,1) void gq_k(const ushort* __restrict__ kpost,
   const float2* __restrict__ db, const int* __restrict__ cu, float* __restrict__ gbuf)
{
  __shared__ float kls[8][64];
  __shared__ float dls[8];
  __shared__ float bls[8];
  int slot = blockIdx.x, h = blockIdx.y;
  int s=-1, n=0, te=0, L=0, st0=0;
  for (int ss=0; ss<NSEG; ss++){
    int st = cu[ss], en = cu[ss+1];
    int base = (st>>3) + ss;
    int nb = (en - st + 7) >> 3;
    if (slot >= base && slot < base + nb){ s=ss; n=slot-base; te=en-1; L=en-st; st0=st; }
  }
  if (s < 0) return;
  int lane = threadIdx.x;
  int vl = lane>>3, kq = lane&7;
  int j = 8*n + vl;
  bool ok = j < L;
  int t = ok ? (te - j) : st0;
  uint4 kv = *(const uint4*)(kpost + (size_t)t*KD + h*HK + kq*8);
  float f0,f1,f2,f3,f4,f5,f6,f7;
  unpack2(kv.x,f0,f1); unpack2(kv.y,f2,f3); unpack2(kv.z,f4,f5); unpack2(kv.w,f6,f7);
  if (!ok){ f0=0;f1=0;f2=0;f3=0;f4=0;f5=0;f6=0;f7=0; }
  float4 w0; w0.x=f0; w0.y=f1; w0.z=f2; w0.w=f3;
  float4 w1; w1.x=f4; w1.y=f5; w1.z=f6; w1.w=f7;
  *(float4*)&kls[vl][kq*8]   = w0;
  *(float4*)&kls[vl][kq*8+4] = w1;
  if (kq==0){
    float dd = 1.f, bb = 0.f;
    if (ok){ float2 g = db[(size_t)t*NH + h]; dd = g.x; bb = g.y; }
    dls[vl] = dd; bls[vl] = bb;
  }
  __syncthreads();
  float out = 0.f;
  if (lane < 28){
    int i = 1, base = 0;
    while (lane >= base + i){ base += i; i++; }
    int m = lane - base;
    const float4* pm = (const float4*)kls[m];
    const float4* pi = (const float4*)kls[i];
    float g = 0.f;
    #pragma unroll
    for (int d=0; d<16; d++){
      float4 xa = pm[d], xb = pi[d];
      g += xa.x*xb.x + xa.y*xb.y + xa.z*xb.z + xa.w*xb.w;
    }
    float W = 1.f;
    for (int l=m; l<i; l++) W *= dls[l];
    out = W * bls[m] * g;
  } else if (lane < 36){
    int i0 = lane - 28;
    float P = 1.f;
    for (int l=0; l<=i0; l++) P *= dls[l];
    out = P;
  } else if (lane < 44){
    int m = lane - 36;
    float W = 1.f;
    for (int l=m; l<8; l++) W *= dls[l];
    out = W * bls[m];
  } else if (lane < 52){
    out = bls[lane-44];
  }
  if (lane < 52) gbuf[((size_t)slot*NH + h)*52 + lane] = out;
}

// helper: map (slot) -> segment/superblock
__device__ __forceinline__ int sb_locate(const int* cu, int slot,
   int& m, int& start, int& te, int& L, int& gb)
{
  int acc = 0;
  int sfound = -1;
  for (int ss=0; ss<NSEG; ss++){
    int st = cu[ss], en = cu[ss+1];
    int Ls = en - st, nb8 = (Ls+7)>>3, nsb = (nb8+63)>>6;
    if (slot >= acc && slot < acc + nsb){
      sfound = ss; m = slot - acc; start = st; te = en-1; L = Ls; gb = (st>>3)+ss;
    }
    acc += nsb;
  }
  return sfound;
}

// ---------------- msb: superblock composite matrix, column-split, k register-cached ----
__global__ __launch_bounds__(512,1) void msb_k(const ushort* __restrict__ kpost,
   const float* __restrict__ gbuf, const int* __restrict__ cu, float* __restrict__ mbuf)
{
  __shared__ float kls[2][8][64];   // [buf][j][dim]
  int slot = blockIdx.x, h = blockIdx.y;
  int m, start, te, L, gb;
  int s = sb_locate(cu, slot, m, start, te, L, gb);
  if (s < 0) return;
  int nb8 = (L+7)>>3;
  int n0 = m*64, n1 = min(nb8, n0+64);
  int tid = threadIdx.x;
  int lane = tid & 63;
  int wv = tid >> 6;
  int cl = lane >> 3, kq = lane & 7;
  int col = wv*8 + cl;
  int d0 = kq*8;
  const ushort* kbase = kpost + h*HK;
  float r0 = (d0+0==col)?1.f:0.f, r1 = (d0+1==col)?1.f:0.f;
  float r2 = (d0+2==col)?1.f:0.f, r3 = (d0+3==col)?1.f:0.f;
  float r4 = (d0+4==col)?1.f:0.f, r5 = (d0+5==col)?1.f:0.f;
  float r6 = (d0+6==col)?1.f:0.f, r7 = (d0+7==col)?1.f:0.f;
  {
    int jj = 8*n0 + wv; int td = (jj<L) ? (te-jj) : start;
    kls[0][wv][lane] = b2f(kbase[(size_t)td*KD + lane]);
  }
  __syncthreads();
  int buf = 0;
  for (int n=n0; n<n1; n++){
    // stage next k block (loads stay in flight across compute)
    {
      int nn = (n+1<n1) ? n+1 : n;
      int jj = 8*nn + wv; int td = (jj<L) ? (te-jj) : start;
      kls[buf^1][wv][lane] = b2f(kbase[(size_t)td*KD + lane]);
    }
    const float4* g4 = (const float4*)(gbuf + ((size_t)(gb+n)*NH + h)*52);
    float4 q0=g4[0], q1=g4[1], q2=g4[2], q3=g4[3], q4=g4[4], q5=g4[5], q6=g4[6],
           q7=g4[7], q8=g4[8], q9=g4[9], q10=g4[10];
    // cache this block's k in registers (read LDS once; reuse for dot AND update)
    float4 ka[8], kb4[8];
    #pragma unroll
    for (int j=0;j<8;j++){
      ka[j]  = *(const float4*)&kls[buf][j][d0];
      kb4[j] = *(const float4*)&kls[buf][j][d0+4];
    }
    float aa[8];
    #pragma unroll
    for (int j=0;j<8;j++){
      float xx = ka[j].x*r0 + ka[j].y*r1;
      xx = fmaf(ka[j].z, r2, xx); xx = fmaf(ka[j].w, r3, xx);
      xx = fmaf(kb4[j].x, r4, xx); xx = fmaf(kb4[j].y, r5, xx);
      xx = fmaf(kb4[j].z, r6, xx); xx = fmaf(kb4[j].w, r7, xx);
      aa[j] = xx;
    }
    #pragma unroll
    for (int j=0;j<8;j++){
      aa[j] += __shfl_xor(aa[j],1);
      aa[j] += __shfl_xor(aa[j],2);
      aa[j] += __shfl_xor(aa[j],4);
    }
    float a0=aa[0],a1=aa[1],a2=aa[2],a3=aa[3],a4=aa[4],a5=aa[5],a6=aa[6],a7=aa[7];
    float c0 = a0;
    float c1 = q7.x*a1 - q0.x*c0;
    float c2 = q7.y*a2 - q0.y*c0 - q0.z*c1;
    float c3 = q7.z*a3 - q0.w*c0 - q1.x*c1 - q1.y*c2;
    float c4 = q7.w*a4 - q1.z*c0 - q1.w*c1 - q2.x*c2 - q2.y*c3;
    float c5 = q8.x*a5 - q2.z*c0 - q2.w*c1 - q3.x*c2 - q3.y*c3 - q3.z*c4;
    float c6 = q8.y*a6 - q3.w*c0 - q4.x*c1 - q4.y*c2 - q4.z*c3 - q4.w*c4 - q5.x*c5;
    float c7 = q8.z*a7 - q5.y*c0 - q5.z*c1 - q5.w*c2 - q6.x*c3 - q6.y*c4 - q6.z*c5 - q6.w*c6;
    float gg[8];
    gg[0] = q9.x*c0; gg[1] = q9.y*c1; gg[2] = q9.z*c2; gg[3] = q9.w*c3;
    gg[4] = q10.x*c4; gg[5] = q10.y*c5; gg[6] = q10.z*c6; gg[7] = q10.w*c7;
    float P8 = q8.w;
    r0*=P8; r1*=P8; r2*=P8; r3*=P8; r4*=P8; r5*=P8; r6*=P8; r7*=P8;
    #pragma unroll
    for (int j=0;j<8;j++){
      r0 = fmaf(-gg[j], ka[j].x, r0); r1 = fmaf(-gg[j], ka[j].y, r1);
      r2 = fmaf(-gg[j], ka[j].z, r2); r3 = fmaf(-gg[j], ka[j].w, r3);
      r4 = fmaf(-gg[j], kb4[j].x, r4); r5 = fmaf(-gg[j], kb4[j].y, r5);
      r6 = fmaf(-gg[j], kb4[j].z, r6); r7 = fmaf(-gg[j], kb4[j].w, r7);
    }
    __syncthreads();
    buf ^= 1;
  }
  float* mp = mbuf + ((size_t)slot*NH + h)*4096 + (size_t)col*64 + d0;
  float4 oA; oA.x=r0; oA.y=r1; oA.z=r2; oA.w=r3;
  float4 oB; oB.x=r4; oB.y=r5; oB.z=r6; oB.w=r7;
  *(float4*)&mp[0] = oA;
  *(float4*)&mp[4] = oB;
}

// ---------------- chain: serial r across superblocks (per s,h) ----------------
__global__ __launch_bounds__(64,1) void chain_k(const float* __restrict__ mbuf,
   const float* __restrict__ qf, const int* __restrict__ cu, float* __restrict__ rbuf)
{
  __shared__ float lsr[64];
  int bid = blockIdx.x;
  int s = bid / NH, h = bid % NH;
  int start = cu[s], end = cu[s+1];
  int L = end - start, nb8 = (L+7)>>3, nsb = (nb8+63)>>6;
  int sbase = 0;
  for (int ss=0; ss<s; ss++){
    int Ls = cu[ss+1]-cu[ss];
    sbase += ((((Ls+7)>>3)+63)>>6);
  }
  int lane = threadIdx.x;
  lsr[lane] = qf[(size_t)s*KD + h*HK + lane];
  __syncthreads();
  float r[64];
  #pragma unroll
  for (int i=0;i<64;i++) r[i] = lsr[i];
  for (int mm=0; mm<nsb; mm++){
    int slot = sbase + mm;
    rbuf[((size_t)slot*NH + h)*64 + lane] = lsr[lane];
    if (mm+1 >= nsb) break;
    const float* mb = mbuf + ((size_t)slot*NH + h)*4096 + lane;  // Mt[col][row=lane]
    float y = 0.f;
    #pragma unroll
    for (int col=0; col<64; col++)
      y = fmaf(mb[(size_t)col*64], r[col], y);
    __syncthreads();
    lsr[lane] = y;
    __syncthreads();
    #pragma unroll
    for (int i=0;i<64;i++) r[i] = lsr[i];
  }
}

// ---------------- scan3: per-superblock c' emission, with prefetch ----------
__global__ __launch_bounds__(64,1) void scan3_k(const ushort* __restrict__ kpost,
   const float* __restrict__ gbuf, const float* __restrict__ rbuf,
   const int* __restrict__ cu, float* __restrict__ cbuf)
{
  int slot = blockIdx.x, h = blockIdx.y;
  int m, start, te, L, gb;
  int s = sb_locate(cu, slot, m, start, te, L, gb);
  if (s < 0) return;
  int nb8 = (L+7)>>3;
  int n0 = m*64, n1 = min(nb8, n0+64);
  int lane = threadIdx.x;
  int vl = lane>>3, kq = lane&7;
  const float* rp = rbuf + ((size_t)slot*NH + h)*64 + kq*8;
  float4 rA = *(const float4*)rp;
  float4 rB = *(const float4*)(rp+4);
  float r0=rA.x, r1=rA.y, r2=rA.z, r3=rA.w, r4=rB.x, r5=rB.y, r6=rB.z, r7=rB.w;
  const ushort* kb = kpost + h*HK + kq*8;
  const float4* g4 = (const float4*)(gbuf + ((size_t)(gb+n0)*NH + h)*52);
  float4 q0=g4[0], q1=g4[1], q2=g4[2], q3=g4[3], q4=g4[4], q5=g4[5], q6=g4[6],
         q7=g4[7], q8=g4[8], q9=g4[9], q10=g4[10], q11=g4[11], q12=g4[12];
  uint4 kd;
  {
    int jj = 8*n0 + vl; bool ok = jj < L; int td = ok ? te - jj : start;
    kd = *(const uint4*)(kb + (size_t)td*KD);
    if (!ok){ kd.x=0; kd.y=0; kd.z=0; kd.w=0; }
  }
  for (int n=n0; n<n1; n++){
    int np = (n+1<n1) ? n+1 : n;
    const float4* gn = (const float4*)(gbuf + ((size_t)(gb+np)*NH + h)*52);
    float4 p0=gn[0], p1=gn[1], p2=gn[2], p3=gn[3], p4=gn[4], p5=gn[5], p6=gn[6],
           p7=gn[7], p8=gn[8], p9=gn[9], p10=gn[10], p11=gn[11], p12=gn[12];
    uint4 kdn; bool okn;
    {
      int jj = 8*np + vl; okn = jj < L; int td = okn ? te - jj : start;
      kdn = *(const uint4*)(kb + (size_t)td*KD);
    }
    int jj = 8*n + vl;
    int tb = te - 8*n;
    int t0c = max(tb-0, start), t1c = max(tb-1, start), t2c = max(tb-2, start), t3c = max(tb-3, start);
    int t4c = max(tb-4, start), t5c = max(tb-5, start), t6c = max(tb-6, start), t7c = max(tb-7, start);
    uint4 km0 = *(const uint4*)(kb + (size_t)t0c*KD);
    uint4 km1 = *(const uint4*)(kb + (size_t)t1c*KD);
    uint4 km2 = *(const uint4*)(kb + (size_t)t2c*KD);
    uint4 km3 = *(const uint4*)(kb + (size_t)t3c*KD);
    uint4 km4 = *(const uint4*)(kb + (size_t)t4c*KD);
    uint4 km5 = *(const uint4*)(kb + (size_t)t5c*KD);
    uint4 km6 = *(const uint4*)(kb + (size_t)t6c*KD);
    uint4 km7 = *(const uint4*)(kb + (size_t)t7c*KD);
    float kk0,kk1,kk2,kk3,kk4,kk5,kk6,kk7;
    unpack2(kd.x, kk0, kk1); unpack2(kd.y, kk2, kk3);
    unpack2(kd.z, kk4, kk5); unpack2(kd.w, kk6, kk7);
    float pa = r0*kk0, pb = r1*kk1;
    pa = fmaf(r2, kk2, pa); pb = fmaf(r3, kk3, pb);
    pa = fmaf(r4, kk4, pa); pb = fmaf(r5, kk5, pb);
    pa = fmaf(r6, kk6, pa); pb = fmaf(r7, kk7, pb);
    float part = pa + pb;
    part += __shfl_xor(part, 1); part += __shfl_xor(part, 2); part += __shfl_xor(part, 4);
    float a0 = __shfl(part, 0*8+kq), a1 = __shfl(part, 1*8+kq);
    float a2 = __shfl(part, 2*8+kq), a3 = __shfl(part, 3*8+kq);
    float a4 = __shfl(part, 4*8+kq), a5 = __shfl(part, 5*8+kq);
    float a6 = __shfl(part, 6*8+kq), a7 = __shfl(part, 7*8+kq);
    float c0 = a0;
    float c1 = q7.x*a1 - q0.x*c0;
    float c2 = q7.y*a2 - q0.y*c0 - q0.z*c1;
    float c3 = q7.z*a3 - q0.w*c0 - q1.x*c1 - q1.y*c2;
    float c4 = q7.w*a4 - q1.z*c0 - q1.w*c1 - q2.x*c2 - q2.y*c3;
    float c5 = q8.x*a5 - q2.z*c0 - q2.w*c1 - q3.x*c2 - q3.y*c3 - q3.z*c4;
    float c6 = q8.y*a6 - q3.w*c0 - q4.x*c1 - q4.y*c2 - q4.z*c3 - q4.w*c4 - q5.x*c5;
    float c7 = q8.z*a7 - q5.y*c0 - q5.z*c1 - q5.w*c2 - q6.x*c3 - q6.y*c4 - q6.z*c5 - q6.w*c6;
    {
      float cw = vl==0?c0: vl==1?c1: vl==2?c2: vl==3?c3: vl==4?c4: vl==5?c5: vl==6?c6: c7;
      float bw = vl==0?q11.x: vl==1?q11.y: vl==2?q11.z: vl==3?q11.w:
                 vl==4?q12.x: vl==5?q12.y: vl==6?q12.z: q12.w;
      if (kq == 0 && jj < L) cbuf[(size_t)(te-jj)*NH + h] = bw*cw;
    }
    float g0 = q9.x*c0, g1 = q9.y*c1, g2 = q9.z*c2, g3 = q9.w*c3;
    float g4_= q10.x*c4, g5 = q10.y*c5, g6 = q10.z*c6, g7 = q10.w*c7;
    float P8 = q8.w;
    r0*=P8; r1*=P8; r2*=P8; r3*=P8; r4*=P8; r5*=P8; r6*=P8; r7*=P8;
    float e0,e1,e2,e3,e4,e5,e6,e7;
#define UPD(KM,GM) \
    unpack2(KM.x,e0,e1); unpack2(KM.y,e2,e3); unpack2(KM.z,e4,e5); unpack2(KM.w,e6,e7); \
    r0 = fmaf(-GM, e0, r0); r1 = fmaf(-GM, e1, r1); r2 = fmaf(-GM, e2, r2); r3 = fmaf(-GM, e3, r3); \
    r4 = fmaf(-GM, e4, r4); r5 = fmaf(-GM, e5, r5); r6 = fmaf(-GM, e6, r6); r7 = fmaf(-GM, e7, r7);
    UPD(km0,g0) UPD(km1,g1) UPD(km2,g2) UPD(km3,g3)
    UPD(km4,g4_) UPD(km5,g5) UPD(km6,g6) UPD(km7,g7)
#undef UPD
    q0=p0; q1=p1; q2=p2; q3=p3; q4=p4; q5=p5; q6=p6; q7=p7; q8=p8; q9=p9; q10=p10; q11=p11; q12=p12;
    if (!okn){ kdn.x=0; kdn.y=0; kdn.z=0; kdn.w=0; }
    kd = kdn;
  }
}

// ---------------- zero obuf ----------------
__global__ void zerok(float* __restrict__ p, int n){
  int i = blockIdx.x*256 + threadIdx.x;
  if (i < n) p[i] = 0.f;
}

// ---------------- o gemv, t-chunked with atomics ----------------
__global__ __launch_bounds__(128,1) void ogemv2_k(const ushort* __restrict__ vpost,
   const float* __restrict__ cbuf, const int* __restrict__ cu, float* __restrict__ obuf)
{
  int bid = blockIdx.x;
  int ch = bid % OCH;
  int sh = bid / OCH;
  int s = sh / NH, h = sh % NH;
  int start = cu[s], end = cu[s+1];
  int L = end - start;
  int clen = (L + OCH - 1) / OCH;
  int t0 = start + ch*clen;
  int t1 = min(end, t0 + clen);
  if (t0 >= t1) return;
  int v = threadIdx.x;
  const ushort* vp = vpost + h*HV + v;
  const float* cp = cbuf + h;
  float o0=0,o1=0,o2=0,o3=0,o4=0,o5=0,o6=0,o7=0;
  int t = t0;
  for (; t+8 <= t1; t+=8){
    o0 = fmaf(cp[(size_t)(t+0)*NH], b2f(vp[(size_t)(t+0)*VD]), o0);
    o1 = fmaf(cp[(size_t)(t+1)*NH], b2f(vp[(size_t)(t+1)*VD]), o1);
    o2 = fmaf(cp[(size_t)(t+2)*NH], b2f(vp[(size_t)(t+2)*VD]), o2);
    o3 = fmaf(cp[(size_t)(t+3)*NH], b2f(vp[(size_t)(t+3)*VD]), o3);
    o4 = fmaf(cp[(size_t)(t+4)*NH], b2f(vp[(size_t)(t+4)*VD]), o4);
    o5 = fmaf(cp[(size_t)(t+5)*NH], b2f(vp[(size_t)(t+5)*VD]), o5);
    o6 = fmaf(cp[(size_t)(t+6)*NH], b2f(vp[(size_t)(t+6)*VD]), o6);
    o7 = fmaf(cp[(size_t)(t+7)*NH], b2f(vp[(size_t)(t+7)*VD]), o7);
  }
  for (; t<t1; t++) o0 = fmaf(cp[(size_t)t*NH], b2f(vp[(size_t)t*VD]), o0);
  float o = ((o0+o1)+(o2+o3)) + ((o4+o5)+(o6+o7));
  atomicAdd(&obuf[(size_t)s*VD + h*HV + v], o);
}

// ---------------- o-norm + gate + silu ----------------
__global__ __launch_bounds__(256,1) void gate_k(const float* __restrict__ obuf,
   const float* __restrict__ hn_ends, const float* __restrict__ Wg,
   const float* __restrict__ onw, const int* __restrict__ cu, float* __restrict__ og)
{
  __shared__ float red[4];
  __shared__ float hrow[H_DIM];
  int tid = threadIdx.x;
  int s = blockIdx.x / 6, ch = blockIdx.x % 6;
  int cc = ch*256 + tid;
  *(float4*)&hrow[tid*4] = *(const float4*)&hn_ends[(size_t)(s*4+3)*H_DIM + tid*4];
  float o = obuf[(size_t)s*VD + cc];
  float sq = o*o;
  #pragma unroll
  for (int off=1; off<64; off<<=1) sq += __shfl_xor(sq, off);
  int wv = tid>>6, lane = tid&63;
  if (lane==0) red[wv] = sq;
  __syncthreads();
  float ssum = (tid<128) ? (red[0]+red[1]) : (red[2]+red[3]);
  float onr = o * rsqrtf(ssum*(1.f/128.f) + 1e-5f) * onw[cc & 127];
  float acc = 0.f;
  for (int i0=0;i0<H_DIM;i0++)
    acc = fmaf(hrow[i0], Wg[(size_t)i0*VD + cc], acc);
  og[(size_t)s*VD + cc] = onr * acc * sigm(acc);
}

// ---------------- final projection + head ----------------
__global__ __launch_bounds__(256,1) void final_k(const float* __restrict__ og,
   const float* __restrict__ Wo, const float* __restrict__ h_end,
   const float* __restrict__ W_head, const float* __restrict__ b_head,
   float* __restrict__ out)
{
  __shared__ float ogs[VD];
  __shared__ float redp[4];
  int tid = threadIdx.x;
  int s = blockIdx.x;
  for (int j=tid; j<VD; j+=256) ogs[j] = og[(size_t)s*VD + j];
  __syncthreads();
  int c0 = tid*4;
  float4 hh4 = *(const float4*)&h_end[(size_t)s*H_DIM + c0];
  float acc0 = hh4.x, acc1 = hh4.y, acc2 = hh4.z, acc3 = hh4.w;
  for (int j=0;j<VD;j++){
    float ov = ogs[j];
    float4 wo = *(const float4*)&Wo[(size_t)j*H_DIM + c0];
    acc0 = fmaf(ov,wo.x,acc0); acc1 = fmaf(ov,wo.y,acc1);
    acc2 = fmaf(ov,wo.z,acc2); acc3 = fmaf(ov,wo.w,acc3);
  }
  float4 wh = *(const float4*)&W_head[c0];
  float p = acc0*wh.x + acc1*wh.y + acc2*wh.z + acc3*wh.w;
  #pragma unroll
  for (int off=1; off<64; off<<=1) p += __shfl_xor(p, off);
  int wv = tid>>6, lane = tid&63;
  if (lane==0) redp[wv] = p;
  __syncthreads();
  if (tid==0) out[s] = redp[0]+redp[1]+redp[2]+redp[3] + b_head[0];
}

extern "C" void kernel_launch(void* const* d_in, const int* in_sizes, int n_in,
                              void* d_out, int out_size, void* d_ws, size_t ws_size,
                              hipStream_t stream)
{
  const float* x      = (const float*)d_in[0];
  const int*   cu     = (const int*)  d_in[1];
  const int*   atype  = (const int*)  d_in[2];
  const float* ac_tab = (const float*)d_in[3];
  const float* W_in   = (const float*)d_in[4];
  const float* b_in   = (const float*)d_in[5];
  const float* norm_w = (const float*)d_in[6];
  const float* Wq     = (const float*)d_in[7];
  const float* Wk     = (const float*)d_in[8];
  const float* Wv     = (const float*)d_in[9];
  const float* cqw    = (const float*)d_in[10];
  const float* ckw    = (const float*)d_in[11];
  const float* cvw    = (const float*)d_in[12];
  const float* Wb     = (const float*)d_in[13];
  const float* Wa     = (const float*)d_in[14];
  const float* A_log  = (const float*)d_in[15];
  const float* dt_b   = (const float*)d_in[16];
  const float* Wg     = (const float*)d_in[17];
  const float* onw    = (const float*)d_in[18];
  const float* Wo     = (const float*)d_in[19];
  const float* W_head = (const float*)d_in[20];
  const float* b_head = (const float*)d_in[21];
  float* out = (float*)d_out;

  // ---- workspace (~211 MiB peak) ----
  char* w = (char*)d_ws;
  int*    seg     = (int*)w;     w += (size_t)T_TOK*4;
  float*  h_end   = (float*)w;   w += (size_t)NSEG*H_DIM*4;
  float*  hn_ends = (float*)w;   w += (size_t)NSEG*4*H_DIM*4;
  float*  qpre    = (float*)w;   w += (size_t)NSEG*4*KD*4;
  float*  qf      = (float*)w;   w += (size_t)NSEG*KD*4;
  float*  obuf    = (float*)w;   w += (size_t)NSEG*VD*4;
  float*  og      = (float*)w;   w += (size_t)NSEG*VD*4;
  float2* db      = (float2*)w;  w += (size_t)T_TOK*NH*8;
  float*  ba      = (float*)w;   w += (size_t)T_TOK*32*4;
  ushort* wt      = (ushort*)w;  w += (size_t)NCOL*H_DIM*2;
  ushort* side    = (ushort*)w;  w += (size_t)(T_TOK/64)*3*2304*2;
  float*  cbuf    = (float*)w;   w += (size_t)T_TOK*NH*4;
  float*  gbuf    = (float*)w;   w += (size_t)NSLOT*NH*52*4;
  float*  mbuf    = (float*)w;   w += (size_t)MAXSB*NH*4096*4;
  float*  rbuf    = (float*)w;   w += (size_t)MAXSB*NH*64*4;
  ushort* hn_c    = (ushort*)w;  w += (size_t)CHUNK_M*H_DIM*2;
  ushort* kpre    = (ushort*)w;  w += (size_t)T_TOK*KD*2;
  ushort* vpre    = (ushort*)w;  w += (size_t)T_TOK*VD*2;

  hipLaunchKernelGGL(segk,     dim3(T_TOK/256),        dim3(256), 0, stream, cu, seg);
  hipLaunchKernelGGL(build_wt, dim3((NCOL*H_DIM)/256), dim3(256), 0, stream, Wk, Wv, Wb, Wa, wt);
  hipLaunchKernelGGL(zerok,    dim3((NSEG*VD+255)/256),dim3(256), 0, stream, obuf, NSEG*VD);
  for (int c = 0; c < T_TOK/CHUNK_M; c++){
    int row_base = c*CHUNK_M;
    hipLaunchKernelGGL(stage_a,  dim3(CHUNK_M/8), dim3(256), 0, stream,
                       x, atype, ac_tab, W_in, b_in, norm_w, seg, row_base, hn_c, h_end, hn_ends);
    hipLaunchKernelGGL(gemm_bf16, dim3((CHUNK_M/128)*(NCOL/128)), dim3(256), 0, stream,
                       hn_c, wt, row_base, kpre, vpre, ba);
  }
  hipLaunchKernelGGL(dbk,      dim3((T_TOK*NH)/256),   dim3(256), 0, stream, ba, A_log, dt_b, db);
  hipLaunchKernelGGL(side_k,   dim3(T_TOK/64),         dim3(256), 0, stream, kpre, vpre, side);
  hipLaunchKernelGGL(conv_ip,  dim3(T_TOK/64),         dim3(256), 0, stream, kpre, vpre, side, seg, ckw, cvw);
  hipLaunchKernelGGL(qpre_k,   dim3(NSEG*4),           dim3(256), 0, stream, hn_ends, Wq, cu, qpre);
  hipLaunchKernelGGL(qfin_k,   dim3(NSEG),             dim3(256), 0, stream, qpre, cqw, cu, seg, qf);
  hipLaunchKernelGGL(gq_k,     dim3(NSLOT, NH),        dim3(64),  0, stream, kpre, db, cu, gbuf);
  hipLaunchKernelGGL(msb_k,    dim3(MAXSB, NH),        dim3(512), 0, stream, kpre, gbuf, cu, mbuf);
  hipLaunchKernelGGL(chain_k,  dim3(NSEG*NH),          dim3(64),  0, stream, mbuf, qf, cu, rbuf);
  hipLaunchKernelGGL(scan3_k,  dim3(MAXSB, NH),        dim3(64),  0, stream, kpre, gbuf, rbuf, cu, cbuf);
  hipLaunchKernelGGL(ogemv2_k, dim3(NSEG*NH*OCH),      dim3(128), 0, stream, vpre, cbuf, cu, obuf);
  hipLaunchKernelGGL(gate_k,   dim3(NSEG*6),           dim3(256), 0, stream, obuf, hn_ends, Wg, onw, cu, og);
  hipLaunchKernelGGL(final_k,  dim3(NSEG),             dim3(256), 0, stream, og, Wo, h_end, W_head, b_head, out);
}